// Round 7
// baseline (25.566 us; speedup 1.0000x reference)
//
#include <hip/hip_runtime.h>
#include <math.h>

#define BB   4      // batch
#define HH   32     // query heads
#define GG   4      // query groups (also KV heads)
#define HPG  8      // heads per group
#define DD   128    // head dim
#define NCK  128    // number of compressed keys per head
#define SEQ  8192   // key/value sequence length
#define NSEL 16     // selected blocks
#define BLK  64     // block size
#define MAGIC 0x13579BDF

// Single kernel, 256 blocks x 512 threads.
// Phase 1 (producer): block bid computes gemv slice (bh = bid>>1, half = bid&1):
//   64 rows x 8 lanes/row, coalesced; publishes 64 scores (agent-scope) + flag.
// Phase 2 (consumer): block (bg = bid>>4, sown = bid&15) waits for its group's
//   16 slice flags, softmax + group mean + rank selection (R6-proven math),
//   then copies its rank's 64x128 K and V blocks.
// The 16 blocks of a group are exactly the producers of that group's slices.
__global__ __launch_bounds__(512) void fused_nsa_kernel(
    const float* __restrict__ query,
    const float* __restrict__ ck,
    const float* __restrict__ keys,
    const float* __restrict__ values,
    float* __restrict__ scores,     // ws: 4*32*128 floats
    int* __restrict__ flags,        // ws: 256 ints
    float* __restrict__ out)
{
    const int bid = blockIdx.x;      // 0..255
    const int t   = threadIdx.x;     // 0..511

    __shared__ float q_sh[DD];
    __shared__ float redm[2][HPG];
    __shared__ float reds[2][HPG];
    __shared__ float pm[NCK];
    __shared__ int   sel_sh;

    // ---------------- producer: gemv slice ----------------
    {
        const int bh   = bid >> 1;           // 0..127
        const int half = bid & 1;
        const int r    = half * 64 + (t >> 3);
        const int sub  = t & 7;

        if (t < DD) q_sh[t] = query[(size_t)bh * DD + t];
        __syncthreads();

        const float4* c4 = (const float4*)(ck + ((size_t)bh * NCK + r) * DD) + sub;
        const float4* q4 = ((const float4*)q_sh) + sub;
        float s = 0.0f;
        #pragma unroll
        for (int i = 0; i < 4; ++i) {
            float4 a = q4[i * 8];
            float4 c = c4[i * 8];            // 8 lanes -> contiguous 128 B line
            s += a.x * c.x + a.y * c.y + a.z * c.z + a.w * c.w;
        }
        s += __shfl_xor(s, 1);
        s += __shfl_xor(s, 2);
        s += __shfl_xor(s, 4);               // identical on all 8 lanes of a row

        if (sub == 0)
            __hip_atomic_store(&scores[(size_t)bh * NCK + r],
                               s * 0.08838834764831845f,
                               __ATOMIC_RELAXED, __HIP_MEMORY_SCOPE_AGENT);
        __syncthreads();                      // drains the block's stores (vmcnt 0)
        if (t == 0) {
            __threadfence();                  // device-scope visibility
            __hip_atomic_store(&flags[bid], (int)MAGIC,
                               __ATOMIC_RELEASE, __HIP_MEMORY_SCOPE_AGENT);
        }
    }

    // ---------------- consumer: select + gather ----------------
    const int bg   = bid >> 4;               // 0..15
    const int sown = bid & 15;
    const int b    = bg >> 2;
    const int g    = bg & 3;
    const int w    = t >> 6;

    // wait for the 16 slices of this group (flags[16*bg .. 16*bg+15])
    if (t < 16) {
        while (__hip_atomic_load(&flags[bg * 16 + t],
                                 __ATOMIC_ACQUIRE, __HIP_MEMORY_SCOPE_AGENT) != (int)MAGIC)
            __builtin_amdgcn_s_sleep(1);
    }
    __syncthreads();

    float sc[HPG];
    float e[HPG];

    if (t < NCK) {
        #pragma unroll
        for (int j = 0; j < HPG; ++j)
            sc[j] = __hip_atomic_load(&scores[(size_t)(b * HH + g * HPG + j) * NCK + t],
                                      __ATOMIC_RELAXED, __HIP_MEMORY_SCOPE_AGENT);
        #pragma unroll
        for (int j = 0; j < HPG; ++j) {
            float m = sc[j];
            #pragma unroll
            for (int off = 1; off < 64; off <<= 1) m = fmaxf(m, __shfl_xor(m, off));
            if ((t & 63) == 0) redm[w][j] = m;
        }
    }
    __syncthreads();

    if (t < NCK) {
        #pragma unroll
        for (int j = 0; j < HPG; ++j) {
            const float m = fmaxf(redm[0][j], redm[1][j]);
            e[j] = expf(sc[j] - m);
            float ssum = e[j];
            #pragma unroll
            for (int off = 1; off < 64; off <<= 1) ssum += __shfl_xor(ssum, off);
            if ((t & 63) == 0) reds[w][j] = ssum;
        }
    }
    __syncthreads();

    if (t < NCK) {
        float p = 0.0f;
        #pragma unroll
        for (int j = 0; j < HPG; ++j) p += e[j] / (reds[0][j] + reds[1][j]);
        pm[t] = p * 0.125f;
    }
    __syncthreads();

    // rank of row t (stable descending = lax.top_k order)
    if (t < NCK) {
        const float mv = pm[t];
        int rank = 0;
        for (int i = 0; i < NCK; ++i) {
            const float vi = pm[i];
            if (vi > mv || (vi == mv && i < t)) ++rank;
        }
        if (rank == sown) sel_sh = t;         // exactly one thread matches
    }
    __syncthreads();
    const int sel = sel_sh;

    // copy the selected 64x128 K and V blocks (2048 float4 each, 512 threads)
    const size_t src  = ((size_t)bg * SEQ + (size_t)sel * BLK) * DD;
    const size_t dst  = ((size_t)bg * (NSEL * BLK) + (size_t)sown * BLK) * DD;
    const size_t VOFF = (size_t)BB * GG * NSEL * BLK * DD;

    const float4* ks = (const float4*)(keys + src);
    const float4* vs = (const float4*)(values + src);
    float4* kd = (float4*)(out + dst);
    float4* vd = (float4*)(out + VOFF + dst);

    #pragma unroll
    for (int i = 0; i < 4; ++i) kd[i * 512 + t] = ks[i * 512 + t];
    #pragma unroll
    for (int i = 0; i < 4; ++i) vd[i * 512 + t] = vs[i * 512 + t];
}

extern "C" void kernel_launch(void* const* d_in, const int* in_sizes, int n_in,
                              void* d_out, int out_size, void* d_ws, size_t ws_size,
                              hipStream_t stream) {
    const float* query  = (const float*)d_in[0];   // (4,32,1,128)
    const float* ck     = (const float*)d_in[1];   // (4,32,128,128)
    const float* keys   = (const float*)d_in[2];   // (4,4,8192,128)
    const float* values = (const float*)d_in[3];   // (4,4,8192,128)
    float* out = (float*)d_out;

    float* scores = (float*)d_ws;                                  // 64 KB
    int*   flags  = (int*)((char*)d_ws + (size_t)BB * HH * NCK * sizeof(float)); // 1 KB

    fused_nsa_kernel<<<BB * GG * NSEL, 512, 0, stream>>>(query, ck, keys, values,
                                                         scores, flags, out);
}